// Round 1
// 476.670 us; speedup vs baseline: 1.0096x; 1.0096x over previous
//
#include <hip/hip_runtime.h>

#define H 256
#define W 256
#define CIN 16
#define COUT 16
#define OH 254
#define OW 254
#define OHB 12          // output rows per block
#define IRB (OHB + 2)   // 14 input rows staged
#define COLS 259        // cols 0..258 staged (240 + 15 + 3 halo for kw-dummy)
#define NOHG 22         // ceil(254 / 12)
#define NTHREADS 512
#define NWAVES 8
#define TILES (OHB * 16)       // 192 MFMA tiles per block
#define TPW (TILES / NWAVES)   // 24 tiles per wave

typedef int int4v __attribute__((ext_vector_type(4)));
typedef int int2v __attribute__((ext_vector_type(2)));

// pack low bytes of 4 dwords -> 1 dword: [d0.b0, d1.b0, d2.b0, d3.b0]
static __device__ __forceinline__ int pack4(int d0, int d1, int d2, int d3) {
    int t0 = __builtin_amdgcn_perm(d1, d0, 0x00000400);  // [d0.b0, d1.b0, x, x]
    int t1 = __builtin_amdgcn_perm(d3, d2, 0x00000400);  // [d2.b0, d3.b0, x, x]
    return __builtin_amdgcn_perm(t1, t0, 0x05040100);
}

// out[n][co][oh][ow] = 1e-4 * (Sum x*w - 3*Sum(x) - 7*Sum(w) + 3024) + bdeq[co]
// Implicit GEMM: M=16 co, N=16 ow, K=64 = kw(4; kw==3 zero-weight) x cin(16)
// per MFMA; 3 MFMAs over kh. A-lane: m=lane&15 (co), k-chunk=lane>>4 (kw),
// bytes=cin. B-lane: n=lane&15 (ow off), k-chunk=lane>>4 (kw) -> reads the
// packed-cin 16B of pixel col ow0+(lane&15)+(lane>>4). C/D: col=lane&15,
// row=(lane>>4)*4+reg.
// 512 threads (8 waves): same 60KB LDS tile as the 256-thread version but
// 2 blocks/CU x 8 waves = 16 waves/CU (VGPR cap) instead of 8 -> latency hiding.
__global__ __launch_bounds__(NTHREADS, 4) void conv_q8_mfma(
    const int* __restrict__ x, const int* __restrict__ wq,
    const float* __restrict__ bias, float* __restrict__ out)
{
    __shared__ int4v lds_x[IRB * COLS];   // [row*COLS + col], 16 cin bytes/pixel
    __shared__ int4v lds_wA[192];         // [(kh*4 + kw)*16 + co]
    __shared__ int   lds_ci[COUT];        // -7*sumW + 3024
    __shared__ float lds_bf[COUT];        // dequantized bias

    const int tid = threadIdx.x;
    const int ohg = blockIdx.x;
    const int n   = blockIdx.y;
    const int oh0 = ohg * OHB;

    // ---- stage packed A (weights) ----
    if (tid < 192) {
        const int t = tid;
        const int co = t & 15;
        const int kw = (t >> 4) & 3;
        const int kh = t >> 6;
        int4v pk = {0, 0, 0, 0};
        if (kw < 3) {
#pragma unroll
            for (int q = 0; q < 4; ++q) {
                const int* wp = wq + ((co * CIN + q * 4) * 3 + kh) * 3 + kw;
                pk[q] = pack4(wp[0], wp[9], wp[18], wp[27]);
            }
        }
        lds_wA[t] = pk;
    }
    // ---- per-cout constants ----
    if (tid < COUT) {
        int s = 0;
        const int* wc = wq + tid * CIN * 9;
#pragma unroll
        for (int k = 0; k < CIN * 9; ++k) s += wc[k];
        lds_ci[tid] = -7 * s + 144 * 21;
        float r = rintf(bias[tid] * 10000.0f);                // round-half-even
        r = fminf(fmaxf(r, -2147483648.0f), 2147483647.0f);   // clamp int32 range
        lds_bf[tid] = r * 1e-4f;
    }
    // ---- zero the 3 halo columns (256..258) ----
    if (tid < IRB * 4) {
        const int row = tid >> 2;
        const int col = 256 + (tid & 3);
        if (col < COLS) lds_x[row * COLS + col] = (int4v){0, 0, 0, 0};
    }

    // ---- stage input: 2 pixels/thread via dwordx2, packed cin16 -> 16B/pixel ----
    const int* xn = x + (size_t)n * (CIN * H * W);
    for (int t = tid; t < IRB * 128; t += NTHREADS) {
        const int row = t >> 7;
        const int c2 = (t & 127) * 2;
        int ih = oh0 + row;
        if (ih > H - 1) ih = H - 1;   // clamp (rows past image are masked at store)
        const int* p = xn + ih * W + c2;
        int4v pk0, pk1;
#pragma unroll
        for (int q = 0; q < 4; ++q) {
            const int2v d0 = *(const int2v*)(p + (q * 4 + 0) * (H * W));
            const int2v d1 = *(const int2v*)(p + (q * 4 + 1) * (H * W));
            const int2v d2 = *(const int2v*)(p + (q * 4 + 2) * (H * W));
            const int2v d3 = *(const int2v*)(p + (q * 4 + 3) * (H * W));
            pk0[q] = pack4(d0.x, d1.x, d2.x, d3.x);
            pk1[q] = pack4(d0.y, d1.y, d2.y, d3.y);
        }
        lds_x[row * COLS + c2]     = pk0;   // lane stride 32B -> 2-way (free)
        lds_x[row * COLS + c2 + 1] = pk1;
    }
    __syncthreads();

    // ---- compute: 8 waves x 24 tiles (12 oh rows x 16 ow-groups of 16) ----
    const int wave = tid >> 6;
    const int lane = tid & 63;
    const int n16  = lane & 15;
    const int quad = lane >> 4;

    const int4v a0 = lds_wA[(0 * 4 + quad) * 16 + n16];
    const int4v a1 = lds_wA[(1 * 4 + quad) * 16 + n16];
    const int4v a2 = lds_wA[(2 * 4 + quad) * 16 + n16];
    const int ov = (quad < 3) ? 0x01010101 : 0;
    const int4v aones = {ov, ov, ov, ov};

    int   ci_r[4];
    float bf_r[4];
#pragma unroll
    for (int r = 0; r < 4; ++r) {
        ci_r[r] = lds_ci[quad * 4 + r];
        bf_r[r] = lds_bf[quad * 4 + r];
    }

    float* outn = out + (size_t)n * (COUT * OH * OW);
    const int coff = n16 + quad;

    for (int t = wave * TPW; t < wave * TPW + TPW; ++t) {
        const int rl = t >> 4;
        const int g  = t & 15;
        const int oh = oh0 + rl;
        if (oh >= OH) continue;   // wave-uniform
        const int ow0 = g * 16;
        const int c = ow0 + coff;
        const int4v b0 = lds_x[(rl + 0) * COLS + c];
        const int4v b1 = lds_x[(rl + 1) * COLS + c];
        const int4v b2 = lds_x[(rl + 2) * COLS + c];
        int4v acc = {0, 0, 0, 0};
        int4v acs = {0, 0, 0, 0};
        acc = __builtin_amdgcn_mfma_i32_16x16x64_i8(a0, b0, acc, 0, 0, 0);
        acc = __builtin_amdgcn_mfma_i32_16x16x64_i8(a1, b1, acc, 0, 0, 0);
        acc = __builtin_amdgcn_mfma_i32_16x16x64_i8(a2, b2, acc, 0, 0, 0);
        acs = __builtin_amdgcn_mfma_i32_16x16x64_i8(aones, b0, acs, 0, 0, 0);
        acs = __builtin_amdgcn_mfma_i32_16x16x64_i8(aones, b1, acs, 0, 0, 0);
        acs = __builtin_amdgcn_mfma_i32_16x16x64_i8(aones, b2, acs, 0, 0, 0);
        const int sx = acs[0];          // all C rows identical for A=ones
        const int ow = ow0 + n16;
        if (ow < OW) {
#pragma unroll
            for (int r = 0; r < 4; ++r) {
                const int co  = quad * 4 + r;
                const int tot = acc[r] - 3 * sx + ci_r[r];
                outn[(co * OH + oh) * OW + ow] = fmaf(1e-4f, (float)tot, bf_r[r]);
            }
        }
    }
}

extern "C" void kernel_launch(void* const* d_in, const int* in_sizes, int n_in,
                              void* d_out, int out_size, void* d_ws, size_t ws_size,
                              hipStream_t stream) {
    const int*   x    = (const int*)d_in[0];
    const int*   wq   = (const int*)d_in[1];
    const float* bias = (const float*)d_in[2];
    float*       out  = (float*)d_out;

    const int n = in_sizes[0] / (CIN * H * W);   // 64
    dim3 grid(NOHG, n);
    conv_q8_mfma<<<grid, NTHREADS, 0, stream>>>(x, wq, bias, out);
}